// Round 1
// baseline (98.568 us; speedup 1.0000x reference)
//
#include <hip/hip_runtime.h>
#include <math.h>

#define LOG2E_F 1.4426950408889634f
#define LN2_F   0.6931471805599453f

constexpr int Bn = 1024;
constexpr int Tn = 512;
constexpr int Ln = 32;

// Kernel 1: log-partition (forward/backward split), one 64-lane wave per batch.
// lanes 0..31: forward recursion over t in [0, m)   (state = alpha, exp-domain)
// lanes 32..63: backward recursion over t in [m, len) (state = beta, exp-domain)
// m = min(len, 256). Combine: lognorm = lse_j(alpha_{m-1,j} + beta_{m-1,j}).
__global__ __launch_bounds__(64)
void crf_lognorm_kernel(const float* __restrict__ logits,
                        const float* __restrict__ trans,
                        const int* __restrict__ seq_lens,
                        float* __restrict__ lognorm)
{
    __shared__ __align__(16) float buf[2][2][Ln];   // [phase][group][label]

    const int b    = blockIdx.x;
    const int lane = threadIdx.x;     // 0..63
    const int g    = lane >> 5;       // 0 = fw, 1 = bw
    const int j    = lane & 31;       // label index this lane owns

    int len = seq_lens[b];
    len = len < 1 ? 1 : (len > Tn ? Tn : len);
    const int m   = len < (Tn / 2) ? len : (Tn / 2);
    const int Kf  = m - 1;            // forward steps (t = 1..m-1)
    const int Kb  = len - m;          // backward steps (t+1 = len-1 .. m)
    const int Kw  = Kf > Kb ? Kf : Kb;
    const int Kme = (g == 0) ? Kf : Kb;

    const float* xb = logits + (size_t)b * (Tn * Ln);

    // Transition fragment in registers: fw lane j holds column j, bw lane j holds row j.
    float E[Ln];
    float tmax = -3.4e38f;
    #pragma unroll
    for (int i = 0; i < Ln; ++i) {
        const float tv = (g == 0) ? trans[i * Ln + j] : trans[j * Ln + i];
        E[i] = tv;
        tmax = fmaxf(tmax, tv);
    }
    #pragma unroll
    for (int off = 1; off < 64; off <<= 1)
        tmax = fmaxf(tmax, __shfl_xor(tmax, off));        // global max over trans
    const float tmax2 = tmax * LOG2E_F;                   // per-step M increment (log2)
    #pragma unroll
    for (int i = 0; i < Ln; ++i)
        E[i] = exp2f((E[i] - tmax) * LOG2E_F);            // E in [tiny, 1]

    // Init state. fw: s_j = 2^(x0_j*log2e - mx), M = mx. bw: s = 1, M = 0.
    const float a0 = xb[j] * LOG2E_F;
    float mx = a0;
    #pragma unroll
    for (int off = 1; off < 32; off <<= 1)
        mx = fmaxf(mx, __shfl_xor(mx, off));              // group-local (xor<=16 stays in half)
    float s = (g == 0) ? exp2f(a0 - mx) : 1.0f;
    float M = (g == 0) ? mx : 0.0f;

    // Emission pointer: fw walks t = 1,2,...  bw walks t = len-1, len-2, ...
    const int dt = (g == 0) ? Ln : -Ln;
    const float* xp = xb + ((g == 0) ? 1 : (len - 1)) * Ln + j;
    float xv_next = (Kw >= 1) ? *xp : 0.0f;

    for (int k = 1; k <= Kw; ++k) {
        const float xv = xv_next;
        xp += dt;
        if (k < Kw) xv_next = *xp;                        // prefetch next step's emission

        const float gg = exp2f(xv * LOG2E_F);             // 2^(x * log2e)
        float* mybuf = buf[k & 1][g];
        // fw broadcasts s; bw broadcasts s * 2^x (emission applied before transition)
        const float w = (g == 0) ? s : s * gg;
        mybuf[j] = w;
        __syncthreads();                                   // single-wave block: cheap fence

        float q0 = 0.f, q1 = 0.f, q2 = 0.f, q3 = 0.f;
        #pragma unroll
        for (int c = 0; c < 8; ++c) {
            const float4 q = *(const float4*)(mybuf + 4 * c);  // broadcast ds_read_b128
            q0 = fmaf(q.x, E[4 * c + 0], q0);
            q1 = fmaf(q.y, E[4 * c + 1], q1);
            q2 = fmaf(q.z, E[4 * c + 2], q2);
            q3 = fmaf(q.w, E[4 * c + 3], q3);
        }
        const float dot  = (q0 + q1) + (q2 + q3);
        const float snew = (g == 0) ? dot * gg : dot;

        const bool act = (k <= Kme);
        s = act ? snew : s;
        M = act ? (M + tmax2) : M;

        if ((k & 3) == 0) {                                // periodic renorm (exactness-preserving)
            float r = s;
            #pragma unroll
            for (int off = 1; off < 32; off <<= 1)
                r = fmaxf(r, __shfl_xor(r, off));
            r = (r > 0.f) ? r : 1.0f;
            s *= __builtin_amdgcn_rcpf(r);
            M += log2f(r);
        }
        __syncthreads();                                   // order reads before next phase write
    }

    // Combine: lognorm = Mf + Mb + log2( sum_j sf_j * sb_j ), in log2 domain.
    buf[0][g][j] = s;
    __syncthreads();
    float term = buf[0][0][j] * buf[0][1][j];
    #pragma unroll
    for (int off = 1; off < 32; off <<= 1)
        term += __shfl_xor(term, off);
    const float Mo = __shfl_xor(M, 32);
    if (lane == 0)
        lognorm[b] = (M + Mo + log2f(term)) * LN2_F;       // back to natural log
}

// Kernel 2: gold path score (unary + binary) and final output.
__global__ __launch_bounds__(256)
void crf_score_kernel(const float* __restrict__ logits,
                      const float* __restrict__ trans,
                      const int* __restrict__ labels,
                      const int* __restrict__ seq_lens,
                      const float* __restrict__ lognorm,
                      float* __restrict__ out)
{
    const int b   = blockIdx.x;
    const int tid = threadIdx.x;
    int len = seq_lens[b];
    len = len < 1 ? 1 : (len > Tn ? Tn : len);

    const int*   lb = labels + (size_t)b * Tn;
    const float* xb = logits + (size_t)b * (Tn * Ln);

    float acc = 0.f;
    for (int t = tid; t < len; t += 256) {
        const int lt = lb[t];
        acc += xb[t * Ln + lt];
        if (t >= 1) acc += trans[lb[t - 1] * Ln + lt];
    }
    #pragma unroll
    for (int off = 1; off < 64; off <<= 1)
        acc += __shfl_xor(acc, off);

    __shared__ float wred[4];
    const int wid = tid >> 6;
    if ((tid & 63) == 0) wred[wid] = acc;
    __syncthreads();
    if (tid == 0)
        out[b] = (wred[0] + wred[1] + wred[2] + wred[3]) - lognorm[b];
}

extern "C" void kernel_launch(void* const* d_in, const int* in_sizes, int n_in,
                              void* d_out, int out_size, void* d_ws, size_t ws_size,
                              hipStream_t stream) {
    const float* logits   = (const float*)d_in[0];
    const float* trans    = (const float*)d_in[1];
    const int*   labels   = (const int*)d_in[2];
    const int*   seq_lens = (const int*)d_in[3];
    float* out     = (float*)d_out;
    float* lognorm = (float*)d_ws;   // 1024 floats of scratch

    crf_lognorm_kernel<<<Bn, 64, 0, stream>>>(logits, trans, seq_lens, lognorm);
    crf_score_kernel<<<Bn, 256, 0, stream>>>(logits, trans, labels, seq_lens, lognorm, out);
}

// Round 3
// 71.538 us; speedup vs baseline: 1.3778x; 1.3778x over previous
//
#include <hip/hip_runtime.h>
#include <math.h>

#define LOG2E_F 1.4426950408889634f
#define LN2_F   0.6931471805599453f

constexpr int Bn = 1024;
constexpr int Tn = 512;
constexpr int Ln = 32;

// Kernel 1: log-partition, one 64-lane wave per batch, fw/bw split.
// lanes 0..31 (g=0): forward recursion t in [0, m)
// lanes 32..63 (g=1): backward recursion t in [m, len)
// Wave-synchronous: single-wave workgroup, DS pipe is in-order per wave,
// so no barriers are needed for the LDS broadcast round-trip.
__global__ __launch_bounds__(64)
void crf_lognorm_kernel(const float* __restrict__ logits,
                        const float* __restrict__ trans,
                        const int* __restrict__ seq_lens,
                        float* __restrict__ lognorm)
{
    __shared__ __align__(16) float buf[2][2][Ln];   // [phase][group][label]

    const int b    = blockIdx.x;
    const int lane = threadIdx.x;     // 0..63
    const int g    = lane >> 5;       // 0 = fw, 1 = bw
    const int j    = lane & 31;       // label index this lane owns

    int len = seq_lens[b];
    len = len < 1 ? 1 : (len > Tn ? Tn : len);
    const int m   = len < (Tn / 2) ? len : (Tn / 2);
    const int Kf  = m - 1;                 // forward steps
    const int Kb  = len - m;               // backward steps
    const int Kw  = Kf > Kb ? Kf : Kb;
    const int Kme = (g == 0) ? Kf : Kb;
    const int KW4 = (Kw + 3) & ~3;         // round up: inert steps are no-ops

    const float* xb = logits + (size_t)b * (Tn * Ln);

    // Transition fragment: fw lane j holds column j, bw lane j holds row j.
    float E[Ln];
    float tmax = -3.4e38f;
    #pragma unroll
    for (int i = 0; i < Ln; ++i) {
        const float tv = (g == 0) ? trans[i * Ln + j] : trans[j * Ln + i];
        E[i] = tv;
        tmax = fmaxf(tmax, tv);
    }
    #pragma unroll
    for (int off = 1; off < 64; off <<= 1)
        tmax = fmaxf(tmax, __shfl_xor(tmax, off));        // global trans max
    const float tmax2 = tmax * LOG2E_F;                   // per-step M increment
    #pragma unroll
    for (int i = 0; i < Ln; ++i)
        E[i] = __builtin_amdgcn_exp2f((E[i] - tmax) * LOG2E_F);  // E in [e^-1, 1]

    // Init. fw: s_j = 2^(x0_j*log2e - mx), M = mx. bw: s = 1, M = 0.
    const float a0 = xb[j] * LOG2E_F;
    float mx = a0;
    #pragma unroll
    for (int off = 1; off < 32; off <<= 1)
        mx = fmaxf(mx, __shfl_xor(mx, off));              // group-local max
    float s = (g == 0) ? __builtin_amdgcn_exp2f(a0 - mx) : 1.0f;
    float M = (g == 0) ? mx : 0.0f;

    // Emission stream: fw walks t = 1,2,...  bw walks t = len-1, len-2, ...
    // 4-deep register prefetch; clamp below xb (bw can run past t=0 on inert
    // prefetches — value unused, just keep the address in-bounds).
    const int dt = (g == 0) ? Ln : -Ln;
    const float* xp = xb + ((g == 0) ? 1 : (len - 1)) * Ln + j;
    float xn0, xn1, xn2, xn3;
    { const float* p = xp;          if (p < xb) p = xb; xn0 = *p; }
    { const float* p = xp + dt;     if (p < xb) p = xb; xn1 = *p; }
    { const float* p = xp + 2*dt;   if (p < xb) p = xb; xn2 = *p; }
    { const float* p = xp + 3*dt;   if (p < xb) p = xb; xn3 = *p; }
    xp += 4 * dt;

    float* gbuf = &buf[0][g][0];     // phase stride = 64 floats

    for (int k4 = 1; k4 <= KW4; k4 += 4) {
        auto step = [&](int R, float& xn) {
            const int k = k4 + R;
            const float xv = xn;
            // refill this slot for step k+4 (independent, 4-deep in flight)
            { const float* p = xp; if (p < xb) p = xb; xn = *p; }
            xp += dt;

            const float gg = __builtin_amdgcn_exp2f(xv * LOG2E_F);  // 2^(x*log2e)
            float* mb = gbuf + (((R + 1) & 1) << 6);   // k4 odd -> phase static per R
            const float w = (g == 0) ? s : s * gg;     // bw applies emission first
            mb[j] = w;
            __builtin_amdgcn_sched_barrier(0);          // keep reads after write

            float q0 = 0.f, q1 = 0.f, q2 = 0.f, q3 = 0.f, c0 = 1.0f;
            #pragma unroll
            for (int c = 0; c < 8; ++c) {
                const float4 q = *(const float4*)(mb + 4 * c);  // broadcast read
                if (c == 0) c0 = q.x;                   // free renorm constant
                q0 = fmaf(q.x, E[4 * c + 0], q0);
                q1 = fmaf(q.y, E[4 * c + 1], q1);
                q2 = fmaf(q.z, E[4 * c + 2], q2);
                q3 = fmaf(q.w, E[4 * c + 3], q3);
            }
            const float dot  = (q0 + q1) + (q2 + q3);
            const float snew = (g == 0) ? dot * gg : dot;

            const bool act = (k <= Kme);
            s = act ? snew : s;
            M = act ? (M + tmax2) : M;

            if (R == 3) {   // renorm by w[0] (uniform across group) — free read
                s *= __builtin_amdgcn_rcpf(c0);
                M += __builtin_amdgcn_logf(c0);         // v_log_f32 = log2
            }
        };
        step(0, xn0); step(1, xn1); step(2, xn2); step(3, xn3);
    }

    // Combine: lognorm = Mf + Mb + log2( sum_j sf_j * sb_j ).
    gbuf[j] = s;                         // buf[0][g][j]
    __builtin_amdgcn_sched_barrier(0);
    float term = buf[0][0][j] * buf[0][1][j];
    #pragma unroll
    for (int off = 1; off < 32; off <<= 1)
        term += __shfl_xor(term, off);
    const float Mo = __shfl_xor(M, 32);
    if (lane == 0)
        lognorm[b] = (M + Mo + __builtin_amdgcn_logf(term)) * LN2_F;
}

// Kernel 2: gold path score (unary + binary) and final output.
__global__ __launch_bounds__(256)
void crf_score_kernel(const float* __restrict__ logits,
                      const float* __restrict__ trans,
                      const int* __restrict__ labels,
                      const int* __restrict__ seq_lens,
                      const float* __restrict__ lognorm,
                      float* __restrict__ out)
{
    const int b   = blockIdx.x;
    const int tid = threadIdx.x;
    int len = seq_lens[b];
    len = len < 1 ? 1 : (len > Tn ? Tn : len);

    const int*   lb = labels + (size_t)b * Tn;
    const float* xb = logits + (size_t)b * (Tn * Ln);

    float acc = 0.f;
    for (int t = tid; t < len; t += 256) {
        const int lt = lb[t];
        acc += xb[t * Ln + lt];
        if (t >= 1) acc += trans[lb[t - 1] * Ln + lt];
    }
    #pragma unroll
    for (int off = 1; off < 64; off <<= 1)
        acc += __shfl_xor(acc, off);

    __shared__ float wred[4];
    const int wid = tid >> 6;
    if ((tid & 63) == 0) wred[wid] = acc;
    __syncthreads();
    if (tid == 0)
        out[b] = (wred[0] + wred[1] + wred[2] + wred[3]) - lognorm[b];
}

extern "C" void kernel_launch(void* const* d_in, const int* in_sizes, int n_in,
                              void* d_out, int out_size, void* d_ws, size_t ws_size,
                              hipStream_t stream) {
    const float* logits   = (const float*)d_in[0];
    const float* trans    = (const float*)d_in[1];
    const int*   labels   = (const int*)d_in[2];
    const int*   seq_lens = (const int*)d_in[3];
    float* out     = (float*)d_out;
    float* lognorm = (float*)d_ws;   // 1024 floats of scratch

    crf_lognorm_kernel<<<Bn, 64, 0, stream>>>(logits, trans, seq_lens, lognorm);
    crf_score_kernel<<<Bn, 256, 0, stream>>>(logits, trans, labels, seq_lens, lognorm, out);
}